// Round 7
// baseline (351.922 us; speedup 1.0000x reference)
//
#include <hip/hip_runtime.h>
#include <math.h>

// Problem constants
#define BATCH 4
#define SEQ   4096
#define DMODEL 1024
#define HEADS 16
#define HDIM  64
#define CHUNK 64
#define NCHUNK 64
#define NTOK  16384          // BATCH*SEQ
#define QKVC  3072           // 3*DMODEL
#define SCALE_F 0.35355339059327373f  // 64^-0.25
#define ROPE_K 0.4152410118609203f    // log2(10000)/32

typedef unsigned short u16;
typedef _Float16 f16;
typedef __attribute__((ext_vector_type(8))) f16 f16x8;
typedef __attribute__((ext_vector_type(4))) float f32x4;

__device__ __forceinline__ u16 f2h(float f) { f16 h = (f16)f; return *(u16*)&h; }
__device__ __forceinline__ float h2f(u16 u) { f16 h = *(f16*)&u; return (float)h; }
__device__ __forceinline__ void storeC(u16* p, float v) { *p = f2h(v); }
__device__ __forceinline__ void storeC(float* p, float v) { *p = v; }

// Async global->LDS, 16B per lane. LDS dest is wave-uniform base + lane*16.
__device__ __forceinline__ void gload_lds16(const u16* g, u16* l)
{
    __builtin_amdgcn_global_load_lds(
        (const __attribute__((address_space(1))) void*)g,
        (__attribute__((address_space(3))) void*)l, 16, 0, 0);
}

// ---------------------------------------------------------------------------
// fp32 -> fp16 flat convert (n multiple of 1024)
// ---------------------------------------------------------------------------
__global__ __launch_bounds__(256)
void convert_f32_f16(const float* __restrict__ src, u16* __restrict__ dst)
{
    long i = ((long)blockIdx.x * 256 + threadIdx.x) * 4;
    float4 v = *(const float4*)(src + i);
    ushort4 o; o.x = f2h(v.x); o.y = f2h(v.y); o.z = f2h(v.z); o.w = f2h(v.w);
    *(ushort4*)(dst + i) = o;
}

// ---------------------------------------------------------------------------
// Transpose + convert: src fp32 [R][C] -> dst fp16 [C][R], dst row stride dld.
// ---------------------------------------------------------------------------
__global__ __launch_bounds__(256)
void transpose_convert(const float* __restrict__ src, int C,
                       u16* __restrict__ dst, int dld)
{
    __shared__ u16 tile[64][72];
    const int r0 = blockIdx.y * 64, c0 = blockIdx.x * 64;
    const int t = threadIdx.x;
    const int rr = t >> 4, cc4 = (t & 15) * 4;
#pragma unroll
    for (int j = 0; j < 4; ++j) {
        int r = rr + j * 16;
        float4 v = *(const float4*)(src + (long)(r0 + r) * C + c0 + cc4);
        tile[cc4 + 0][r] = f2h(v.x);
        tile[cc4 + 1][r] = f2h(v.y);
        tile[cc4 + 2][r] = f2h(v.z);
        tile[cc4 + 3][r] = f2h(v.w);
    }
    __syncthreads();
#pragma unroll
    for (int j = 0; j < 4; ++j) {
        int c = rr + j * 16;
        ushort4 o = *(ushort4*)&tile[c][cc4];
        *(ushort4*)(dst + (long)(c0 + c) * dld + r0 + cc4) = o;
    }
}

// ---------------------------------------------------------------------------
// MFMA fp16 GEMM: C[M,N] = A[M,K] @ B[K,N], B given TRANSPOSED (BT[N][K]).
// 256x256 tile, 8 waves (2Mx4N, 128x64/wave), ring of 4 K=32 slots, depth-3
// prefetch, ONE barrier + counted vmcnt per K-half (never 0 in steady state).
// SWZ: T1 XCD-chunk block swizzle. Measured (r5): helps GEMM2 (per-XCD
// working set 6 MB ~= L2-resident, ~-30 us) but HURTS GEMM1 (+17%: working
// set 7.3+ MB can't be L2-resident, swizzle only perturbs) -> GEMM1 uses
// identity, GEMM2 uses T1.
// T2 slot-XOR swizzle (measured 0 conflicts), T5 setprio around MFMA.
// ROPE=true: fused RoPE + elu(x*SCALE)+1 epilogue on cols < 2048 (q,k).
// ---------------------------------------------------------------------------
template <typename CT, bool ROPE, bool SWZ>
__global__ __launch_bounds__(512, 2)
void gemm_mfma(const u16* __restrict__ A, int lda,
               const u16* __restrict__ BT, int ldbt,
               CT* __restrict__ C, int ldc, int K)
{
    // 4 ring slots x (A 256x32 + B 256x32) u16 = 4 x 32 KB = 128 KiB
    __shared__ u16 ringA[4][256 * 32];
    __shared__ u16 ringB[4][256 * 32];

    const int tid = threadIdx.x;
    const int gx = gridDim.x;
    long m0, n0;
    if (SWZ) {
        const int nwg = gx * gridDim.y;
        const int bid = blockIdx.y * gx + blockIdx.x;    // dispatch-linear
        const int lid = (nwg & 7) ? bid
                                  : (bid & 7) * (nwg >> 3) + (bid >> 3);
        m0 = (long)(lid / gx) * 256;
        n0 = (long)(lid % gx) * 256;
    } else {
        m0 = (long)blockIdx.y * 256;
        n0 = (long)blockIdx.x * 256;
    }

    const int w = tid >> 6, lane = tid & 63;
    const int wm = w >> 2, wn = w & 3;           // 2 x 4 wave grid
    const int fr = lane & 15, quad = lane >> 4;
    // swizzled 16B-slot offset for fragment reads (u16 units):
    // slot' = quad ^ ((row>>1)&3); row within 16-aligned base -> fr
    const int sw = (quad ^ ((fr >> 1) & 3)) * 8;

    // Staging source map: one gload = 512 thr x 16B = 8 KB = 128 rows of 64B.
    // LDS chunk c = tid: row = c>>2, slot = c&3; inverse-swizzled source col.
    const int srow = tid >> 2;
    const int scol = ((tid & 3) ^ ((tid >> 3) & 3)) * 8;
    const u16* ga = A  + (m0 + srow) * (long)lda  + scol;
    const u16* gb = BT + (n0 + srow) * (long)ldbt + scol;
    const long a128 = 128 * (long)lda, b128 = 128 * (long)ldbt;

    f32x4 acc[8][4];
#pragma unroll
    for (int i = 0; i < 8; ++i)
#pragma unroll
        for (int j = 0; j < 4; ++j)
#pragma unroll
            for (int r = 0; r < 4; ++r) acc[i][j][r] = 0.0f;

    // stage halves of one K-slot (2 gloads each -> vmcnt += 2)
    auto STAGE_A = [&](int h) {
        u16* la = &ringA[h & 3][w * 512];
        const long ko = (long)h << 5;
        gload_lds16(ga + ko,        la);
        gload_lds16(ga + ko + a128, la + 4096);
    };
    auto STAGE_B = [&](int h) {
        u16* lb = &ringB[h & 3][w * 512];
        const long ko = (long)h << 5;
        gload_lds16(gb + ko,        lb);
        gload_lds16(gb + ko + b128, lb + 4096);
    };

    // prologue: stage slots 0..2 (12 gloads), validate slot 0
    STAGE_A(0); STAGE_B(0);
    STAGE_A(1); STAGE_B(1);
    STAGE_A(2); STAGE_B(2);
    asm volatile("s_waitcnt vmcnt(8)" ::: "memory");   // slot 0 landed (mine)
    __builtin_amdgcn_s_barrier();                      // slot 0 valid block-wide

    const int NH = K >> 5;                             // 32 for K=1024
    for (int h = 0; h < NH; ++h) {
        const u16* As_ = ringA[h & 3];
        const u16* Bs_ = ringB[h & 3];
        f16x8 af0[4], af1[4], bf[4];

        // --- window top: reads for this slot + stage A-half of h+3 ---
#pragma unroll
        for (int mi = 0; mi < 4; ++mi)
            af0[mi] = *(const f16x8*)&As_[(wm * 128 + mi * 16 + fr) * 32 + sw];
#pragma unroll
        for (int nj = 0; nj < 4; ++nj)
            bf[nj] = *(const f16x8*)&Bs_[(wn * 64 + nj * 16 + fr) * 32 + sw];
        if (h < NH - 3) STAGE_A(h + 3);   // writes slot (h-1)&3: reads drained at B(h-1)

        // --- MFMA cluster 0 (mi 0..3) ---
        __builtin_amdgcn_s_setprio(1);
#pragma unroll
        for (int mi = 0; mi < 4; ++mi)
#pragma unroll
            for (int nj = 0; nj < 4; ++nj)
                acc[mi][nj] = __builtin_amdgcn_mfma_f32_16x16x32_f16(
                    af0[mi], bf[nj], acc[mi][nj], 0, 0, 0);
        __builtin_amdgcn_s_setprio(0);

        // --- second half reads + stage B-half of h+3 ---
#pragma unroll
        for (int mi = 0; mi < 4; ++mi)
            af1[mi] = *(const f16x8*)&As_[(wm * 128 + (mi + 4) * 16 + fr) * 32 + sw];
        if (h < NH - 3) STAGE_B(h + 3);

        // --- single sync point per slot: validate slot h+1, fence reads ---
        if (h <= NH - 4) {
            asm volatile("s_waitcnt vmcnt(8)" ::: "memory");   // slot h+1 landed
        } else if (h == NH - 3) {
            asm volatile("s_waitcnt vmcnt(4)" ::: "memory");
        } else if (h == NH - 2) {
            asm volatile("s_waitcnt vmcnt(0)" ::: "memory");
        }
        if (h < NH - 1) {
            asm volatile("s_waitcnt lgkmcnt(0)" ::: "memory"); // my slot-h reads done
            __builtin_amdgcn_s_barrier();                      // block-wide rendezvous
        }

        // --- MFMA cluster 1 (mi 4..7, operands pre-drained) ---
        __builtin_amdgcn_s_setprio(1);
#pragma unroll
        for (int mi = 0; mi < 4; ++mi)
#pragma unroll
            for (int nj = 0; nj < 4; ++nj)
                acc[mi + 4][nj] = __builtin_amdgcn_mfma_f32_16x16x32_f16(
                    af1[mi], bf[nj], acc[mi + 4][nj], 0, 0, 0);
        __builtin_amdgcn_s_setprio(0);
    }

    // C/D: col = lane&15 (+16*nj), row = quad*4 + r (+16*mi)
    const long cm = m0 + wm * 128 + quad * 4;
    const long cn = n0 + wn * 64 + fr;

    if (ROPE && cn < 2048) {
        // lane's 4 cols within its 64-aligned head: fr, fr+16, fr+32, fr+48.
        // rope pairs: (nj0,nj2) with d2=fr; (nj1,nj3) with d2=fr+16.
        const float invf0 = exp2f(-(float)fr * ROPE_K);
        const float invf1 = exp2f(-(float)(fr + 16) * ROPE_K);
#pragma unroll
        for (int mi = 0; mi < 8; ++mi)
#pragma unroll
            for (int r = 0; r < 4; ++r) {
                long row = cm + mi * 16 + r;
                float n = (float)(int)(row & (SEQ - 1));
                float s0, c0, s1, c1;
                __sincosf(n * invf0, &s0, &c0);
                __sincosf(n * invf1, &s1, &c1);
                float x1 = acc[mi][0][r], x2 = acc[mi][2][r];
                float x3 = acc[mi][1][r], x4 = acc[mi][3][r];
                float u1 = (x1 * c0 - x2 * s0) * SCALE_F;
                float u2 = (x1 * s0 + x2 * c0) * SCALE_F;
                float u3 = (x3 * c1 - x4 * s1) * SCALE_F;
                float u4 = (x3 * s1 + x4 * c1) * SCALE_F;
                u1 = (u1 > 0.0f) ? (u1 + 1.0f) : __expf(u1);
                u2 = (u2 > 0.0f) ? (u2 + 1.0f) : __expf(u2);
                u3 = (u3 > 0.0f) ? (u3 + 1.0f) : __expf(u3);
                u4 = (u4 > 0.0f) ? (u4 + 1.0f) : __expf(u4);
                CT* pr = C + row * ldc + cn;
                storeC(pr, u1); storeC(pr + 16, u3);
                storeC(pr + 32, u2); storeC(pr + 48, u4);
            }
    } else {
#pragma unroll
        for (int mi = 0; mi < 8; ++mi)
#pragma unroll
            for (int nj = 0; nj < 4; ++nj)
#pragma unroll
                for (int r = 0; r < 4; ++r)
                    storeC(&C[(cm + mi * 16 + r) * ldc + cn + nj * 16], acc[mi][nj][r]);
    }
}

// ---------------------------------------------------------------------------
// Per-(b,h,chunk): S[m][d] = sum_t V[t][m] K[t][d]  (= (K^T V)^T, fp16),
// ksum[d] = sum_t K[t][d] (fp32). MFMA 16x16x32.
// ---------------------------------------------------------------------------
__global__ __launch_bounds__(256)
void chunk_sums_mfma(const u16* __restrict__ qkv,
                     u16* __restrict__ S, float* __restrict__ ksum)
{
    __shared__ u16 Kt[64][72];   // [d][t]
    __shared__ u16 Vt[64][72];   // [m][t]

    const int blk = blockIdx.x;
    const int c = blk & 63, bh = blk >> 6;
    const int b = bh >> 4, h = bh & 15;
    const int tid = threadIdx.x;
    const long base = (long)(b * SEQ + c * CHUNK) * QKVC + h * HDIM;

#pragma unroll
    for (int j = 0; j < 4; ++j) {
        int i4 = (j * 256 + tid) * 4;
        int t = i4 >> 6, d = i4 & 63;
        const u16* src = qkv + base + (long)t * QKVC + d;
        ushort4 kk = *(const ushort4*)(src + DMODEL);
        ushort4 vv = *(const ushort4*)(src + 2 * DMODEL);
        Kt[d + 0][t] = kk.x; Kt[d + 1][t] = kk.y;
        Kt[d + 2][t] = kk.z; Kt[d + 3][t] = kk.w;
        Vt[d + 0][t] = vv.x; Vt[d + 1][t] = vv.y;
        Vt[d + 2][t] = vv.z; Vt[d + 3][t] = vv.w;
    }
    __syncthreads();

    const int w = tid >> 6, lane = tid & 63;
    const int fr = lane & 15, quad = lane >> 4;

    // D[m][d] = sum_t Vt[m][t] * K[t][d];  A = Vt, B-op layout [d][t] = Kt
    f16x8 af0 = *(const f16x8*)&Vt[w * 16 + fr][quad * 8];
    f16x8 af1 = *(const f16x8*)&Vt[w * 16 + fr][32 + quad * 8];
    f32x4 acc[4];
#pragma unroll
    for (int j = 0; j < 4; ++j)
#pragma unroll
        for (int r = 0; r < 4; ++r) acc[j][r] = 0.0f;
#pragma unroll
    for (int j = 0; j < 4; ++j) {
        f16x8 b0 = *(const f16x8*)&Kt[j * 16 + fr][quad * 8];
        f16x8 b1 = *(const f16x8*)&Kt[j * 16 + fr][32 + quad * 8];
        acc[j] = __builtin_amdgcn_mfma_f32_16x16x32_f16(af0, b0, acc[j], 0, 0, 0);
        acc[j] = __builtin_amdgcn_mfma_f32_16x16x32_f16(af1, b1, acc[j], 0, 0, 0);
    }
    const long sb = (long)blk * 4096;
    const int mrow = w * 16 + quad * 4;
#pragma unroll
    for (int j = 0; j < 4; ++j)
#pragma unroll
        for (int r = 0; r < 4; ++r)
            S[sb + (mrow + r) * 64 + j * 16 + fr] = f2h(acc[j][r]);

    if (tid < 64) {
        float s = 0.0f;
        for (int t = 0; t < 64; ++t) s += h2f(Kt[tid][t]);
        ksum[(long)blk * 64 + tid] = s;
    }
}

// ---------------------------------------------------------------------------
// Exclusive prefix scan over chunks (per bh): S (fp16) and ksum (fp32).
// ---------------------------------------------------------------------------
__global__ __launch_bounds__(256)
void scan_kernel(u16* __restrict__ S, float* __restrict__ ksum)
{
    const int blk = blockIdx.x;
    const int slice = blk & 15, bh = blk >> 4;
    const int p = slice * 256 + threadIdx.x;
    const long base = (long)bh * NCHUNK * 4096 + p;
    float acc = 0.0f;
    for (int c = 0; c < NCHUNK; ++c) {
        long idx = base + (long)c * 4096;
        float tmp = h2f(S[idx]);
        S[idx] = f2h(acc);
        acc += tmp;
    }
    if (slice == 0 && threadIdx.x < 64) {
        const long kb = (long)bh * NCHUNK * 64 + threadIdx.x;
        float ka = 0.0f;
        for (int c = 0; c < NCHUNK; ++c) {
            float t = ksum[kb + (long)c * 64];
            ksum[kb + (long)c * 64] = ka;
            ka += t;
        }
    }
}

// ---------------------------------------------------------------------------
// Per-(b,h,chunk) output via MFMA:
//   Sc = causal(Q K^T); out = Sc @ V + Q @ KV_prefix; out /= denom.
// In place over the q slice. S holds KV^T prefix ([m][d]).
// ---------------------------------------------------------------------------
__global__ __launch_bounds__(256)
void chunk_out_mfma(u16* __restrict__ qkv,
                    const u16* __restrict__ S, const float* __restrict__ ksum)
{
    __shared__ u16 Qs[64][72];    // [t][d]
    __shared__ u16 Ks[64][72];    // [s][d]  (B-op for QK^T)
    __shared__ u16 Vt[64][72];    // [m][s]  (B-op for Sc@V)
    __shared__ u16 KVt[64][72];   // [m][d]  (B-op for Q@KV)
    __shared__ u16 Sch[64][72];   // [t][s]  masked scores (A-op for Sc@V)
    __shared__ float kss[64];
    __shared__ float den[64];

    const int blk = blockIdx.x;
    const int c = blk & 63, bh = blk >> 6;
    const int b = bh >> 4, h = bh & 15;
    const int tid = threadIdx.x;
    const long base = (long)(b * SEQ + c * CHUNK) * QKVC + h * HDIM;

#pragma unroll
    for (int j = 0; j < 4; ++j) {
        int i4 = (j * 256 + tid) * 4;
        int t = i4 >> 6, d = i4 & 63;
        const u16* src = qkv + base + (long)t * QKVC + d;
        *(ushort4*)&Qs[t][d] = *(const ushort4*)(src);
        *(ushort4*)&Ks[t][d] = *(const ushort4*)(src + DMODEL);
        ushort4 vv = *(const ushort4*)(src + 2 * DMODEL);
        Vt[d + 0][t] = vv.x; Vt[d + 1][t] = vv.y;
        Vt[d + 2][t] = vv.z; Vt[d + 3][t] = vv.w;
        *(ushort4*)&KVt[t][d] = *(const ushort4*)(S + (long)blk * 4096 + i4);
    }
    if (tid < 64) kss[tid] = ksum[(long)blk * 64 + tid];
    __syncthreads();

    const int w = tid >> 6, lane = tid & 63;
    const int fr = lane & 15, quad = lane >> 4;
    const int trow = w * 16 + quad * 4;   // C-layout row base

    // --- Sc = Q K^T (wave w: rows w*16..+16) ---
    f16x8 aq0 = *(const f16x8*)&Qs[w * 16 + fr][quad * 8];
    f16x8 aq1 = *(const f16x8*)&Qs[w * 16 + fr][32 + quad * 8];
    f32x4 sc[4];
#pragma unroll
    for (int j = 0; j < 4; ++j)
#pragma unroll
        for (int r = 0; r < 4; ++r) sc[j][r] = 0.0f;
#pragma unroll
    for (int j = 0; j < 4; ++j) {
        f16x8 b0 = *(const f16x8*)&Ks[j * 16 + fr][quad * 8];
        f16x8 b1 = *(const f16x8*)&Ks[j * 16 + fr][32 + quad * 8];
        sc[j] = __builtin_amdgcn_mfma_f32_16x16x32_f16(aq0, b0, sc[j], 0, 0, 0);
        sc[j] = __builtin_amdgcn_mfma_f32_16x16x32_f16(aq1, b1, sc[j], 0, 0, 0);
    }
    // causal mask + store fp16
#pragma unroll
    for (int j = 0; j < 4; ++j)
#pragma unroll
        for (int r = 0; r < 4; ++r) {
            int t = trow + r, s = j * 16 + fr;
            Sch[t][s] = f2h(s <= t ? sc[j][r] : 0.0f);
        }
    __syncthreads();

    // --- denominators ---
    if (tid < 64) {
        float dn = 0.0f;
        for (int d = 0; d < 64; ++d) dn += h2f(Qs[tid][d]) * kss[d];
        for (int s = 0; s <= tid; ++s) dn += h2f(Sch[tid][s]);
        den[tid] = 1.0f / fmaxf(dn, 1e-6f);
    }
    __syncthreads();

    // --- out = Sch @ V + Q @ KV ---
    f16x8 as0 = *(const f16x8*)&Sch[w * 16 + fr][quad * 8];
    f16x8 as1 = *(const f16x8*)&Sch[w * 16 + fr][32 + quad * 8];
    f32x4 oc[4];
#pragma unroll
    for (int j = 0; j < 4; ++j)
#pragma unroll
        for (int r = 0; r < 4; ++r) oc[j][r] = 0.0f;
#pragma unroll
    for (int j = 0; j < 4; ++j) {
        f16x8 b0 = *(const f16x8*)&Vt[j * 16 + fr][quad * 8];
        f16x8 b1 = *(const f16x8*)&Vt[j * 16 + fr][32 + quad * 8];
        oc[j] = __builtin_amdgcn_mfma_f32_16x16x32_f16(as0, b0, oc[j], 0, 0, 0);
        oc[j] = __builtin_amdgcn_mfma_f32_16x16x32_f16(as1, b1, oc[j], 0, 0, 0);
        f16x8 k0 = *(const f16x8*)&KVt[j * 16 + fr][quad * 8];
        f16x8 k1 = *(const f16x8*)&KVt[j * 16 + fr][32 + quad * 8];
        oc[j] = __builtin_amdgcn_mfma_f32_16x16x32_f16(aq0, k0, oc[j], 0, 0, 0);
        oc[j] = __builtin_amdgcn_mfma_f32_16x16x32_f16(aq1, k1, oc[j], 0, 0, 0);
    }
    // scale by 1/denom, store in place over q slice
#pragma unroll
    for (int j = 0; j < 4; ++j)
#pragma unroll
        for (int r = 0; r < 4; ++r) {
            int t = trow + r;
            qkv[base + (long)t * QKVC + j * 16 + fr] = f2h(oc[j][r] * den[t]);
        }
}

// ---------------------------------------------------------------------------
extern "C" void kernel_launch(void* const* d_in, const int* in_sizes, int n_in,
                              void* d_out, int out_size, void* d_ws, size_t ws_size,
                              hipStream_t stream)
{
    const float* x     = (const float*)d_in[0];
    const float* w_qkv = (const float*)d_in[1];
    const float* w_out = (const float*)d_in[2];
    float* out = (float*)d_out;

    // Workspace: qkv fp16 only (100.7 MB — proven-safe footprint).
    u16* qkv = (u16*)d_ws;
    // d_out doubles as scratch before the final GEMM writes it:
    u16* xf16  = (u16*)d_out;                         // 16384*1024 fp16
    u16* wqkvT = xf16 + (size_t)NTOK * DMODEL;        // 3072*1024 fp16
    u16* S     = (u16*)d_out;                         // 64*64*4096 fp16 (alias xf16)
    float* ksum = (float*)((char*)d_out + 33554432);  // 64*64*64 fp32 (alias wqkvT)
    // w_outT lives in the dead k-slice of qkv (rows 0..1023, cols 1024..2047)
    u16* woutT = qkv + 1024;                          // [n][k], row stride 3072

    dim3 blk(256);
    dim3 gblk(512);

    // 0) conversions for GEMM1
    convert_f32_f16<<<NTOK * DMODEL / 1024, blk, 0, stream>>>(x, xf16);
    transpose_convert<<<dim3(QKVC / 64, DMODEL / 64), blk, 0, stream>>>(
        w_qkv, QKVC, wqkvT, DMODEL);

    // 1) qkv = x @ w_qkv with fused RoPE+elu on q,k cols (identity swizzle)
    gemm_mfma<u16, true, false><<<dim3(QKVC / 256, NTOK / 256), gblk, 0, stream>>>(
        xf16, DMODEL, wqkvT, DMODEL, qkv, QKVC, DMODEL);

    // 2) chunk-parallel linear attention (all MFMA)
    chunk_sums_mfma<<<64 * NCHUNK, blk, 0, stream>>>(qkv, S, ksum);
    scan_kernel<<<64 * 16, blk, 0, stream>>>(S, ksum);
    chunk_out_mfma<<<64 * NCHUNK, blk, 0, stream>>>(qkv, S, ksum);

    // 3) w_out transpose into dead k-slice, then out = attn @ w_out (T1 swizzle)
    transpose_convert<<<dim3(DMODEL / 64, DMODEL / 64), blk, 0, stream>>>(
        w_out, DMODEL, woutT, QKVC);
    gemm_mfma<float, false, true><<<dim3(DMODEL / 256, NTOK / 256), gblk, 0, stream>>>(
        qkv, QKVC, woutT, QKVC, out, DMODEL, DMODEL);
}

// Round 8
// 347.622 us; speedup vs baseline: 1.0124x; 1.0124x over previous
//
#include <hip/hip_runtime.h>
#include <math.h>

// Problem constants
#define BATCH 4
#define SEQ   4096
#define DMODEL 1024
#define HEADS 16
#define HDIM  64
#define CHUNK 64
#define NCHUNK 64
#define NTOK  16384          // BATCH*SEQ
#define QKVC  3072           // 3*DMODEL
#define SCALE_F 0.35355339059327373f  // 64^-0.25
#define ROPE_K 0.4152410118609203f    // log2(10000)/32

typedef unsigned short u16;
typedef _Float16 f16;
typedef __attribute__((ext_vector_type(8))) f16 f16x8;
typedef __attribute__((ext_vector_type(4))) float f32x4;

__device__ __forceinline__ u16 f2h(float f) { f16 h = (f16)f; return *(u16*)&h; }
__device__ __forceinline__ float h2f(u16 u) { f16 h = *(f16*)&u; return (float)h; }
__device__ __forceinline__ void storeC(u16* p, float v) { *p = f2h(v); }
__device__ __forceinline__ void storeC(float* p, float v) { *p = v; }

// Async global->LDS, 16B per lane. LDS dest is wave-uniform base + lane*16.
__device__ __forceinline__ void gload_lds16(const u16* g, u16* l)
{
    __builtin_amdgcn_global_load_lds(
        (const __attribute__((address_space(1))) void*)g,
        (__attribute__((address_space(3))) void*)l, 16, 0, 0);
}

#define SYNC_IN() do { \
    __builtin_amdgcn_s_barrier(); \
    asm volatile("s_waitcnt lgkmcnt(0)" ::: "memory"); \
    __builtin_amdgcn_sched_barrier(0); } while (0)

#define BAR2() do { \
    __builtin_amdgcn_s_barrier(); \
    __builtin_amdgcn_sched_barrier(0); } while (0)

// ---------------------------------------------------------------------------
// fp32 -> fp16 flat convert (n multiple of 1024)
// ---------------------------------------------------------------------------
__global__ __launch_bounds__(256)
void convert_f32_f16(const float* __restrict__ src, u16* __restrict__ dst)
{
    long i = ((long)blockIdx.x * 256 + threadIdx.x) * 4;
    float4 v = *(const float4*)(src + i);
    ushort4 o; o.x = f2h(v.x); o.y = f2h(v.y); o.z = f2h(v.z); o.w = f2h(v.w);
    *(ushort4*)(dst + i) = o;
}

// ---------------------------------------------------------------------------
// Transpose + convert: src fp32 [R][C] -> dst fp16 [C][R], dst row stride dld.
// ---------------------------------------------------------------------------
__global__ __launch_bounds__(256)
void transpose_convert(const float* __restrict__ src, int C,
                       u16* __restrict__ dst, int dld)
{
    __shared__ u16 tile[64][72];
    const int r0 = blockIdx.y * 64, c0 = blockIdx.x * 64;
    const int t = threadIdx.x;
    const int rr = t >> 4, cc4 = (t & 15) * 4;
#pragma unroll
    for (int j = 0; j < 4; ++j) {
        int r = rr + j * 16;
        float4 v = *(const float4*)(src + (long)(r0 + r) * C + c0 + cc4);
        tile[cc4 + 0][r] = f2h(v.x);
        tile[cc4 + 1][r] = f2h(v.y);
        tile[cc4 + 2][r] = f2h(v.z);
        tile[cc4 + 3][r] = f2h(v.w);
    }
    __syncthreads();
#pragma unroll
    for (int j = 0; j < 4; ++j) {
        int c = rr + j * 16;
        ushort4 o = *(ushort4*)&tile[c][cc4];
        *(ushort4*)(dst + (long)(c0 + c) * dld + r0 + cc4) = o;
    }
}

// ---------------------------------------------------------------------------
// MFMA fp16 GEMM, m201-faithful schedule: 256x256 tile, 8 waves (2Mx4N,
// 128x64/wave), BK=64, 2 LDS buffers, 4 sub-phases per K-tile, each phase
// {reads; stage 1 unit (2 gloads); barrier; lgkmcnt(0); setprio 16-MFMA;
// barrier}. Unit issue slots: tile T.u0 at (T-2).P3 (after that buf's last
// reads drained by (T-2).P2 lgkmcnt+bar), T.u1-3 at (T-1).P0-P2. Gate
// vmcnt(2) at each tile's P3 (allows exactly next-tile.u0 in flight).
// LDS rows 128B with slot^=(row&7) XOR swizzle, both-sides (<=2-way, free).
// SWZ: T1 XCD swizzle — identity for GEMM1 (hurts, r5), T1 for GEMM2.
// ROPE=true: fused RoPE + elu(x*SCALE)+1 epilogue on cols < 2048 (q,k).
// ---------------------------------------------------------------------------
template <typename CT, bool ROPE, bool SWZ>
__global__ __launch_bounds__(512, 2)
void gemm_mfma(const u16* __restrict__ A, int lda,
               const u16* __restrict__ BT, int ldbt,
               CT* __restrict__ C, int ldc, int K)
{
    // 2 bufs x (A 256x64 + B 256x64) u16 = 2 x 64 KB = 128 KiB
    __shared__ u16 bufA[2][256 * 64];
    __shared__ u16 bufB[2][256 * 64];

    const int tid = threadIdx.x;
    const int gx = gridDim.x;
    long m0, n0;
    if (SWZ) {
        const int nwg = gx * gridDim.y;
        const int bid = blockIdx.y * gx + blockIdx.x;
        const int lid = (nwg & 7) ? bid
                                  : (bid & 7) * (nwg >> 3) + (bid >> 3);
        m0 = (long)(lid / gx) * 256;
        n0 = (long)(lid % gx) * 256;
    } else {
        m0 = (long)blockIdx.y * 256;
        n0 = (long)blockIdx.x * 256;
    }

    const int w = tid >> 6, lane = tid & 63;
    const int wm = w >> 2, wn = w & 3;           // 2 x 4 wave grid
    const int fr = lane & 15, quad = lane >> 4;
    const int f7 = fr & 7;

    // Staging geometry: one gload = 64 lanes x 16B = 8 rows x 8 slots.
    // Row for lane = base + (lane>>3); src col slot = (lane&7) ^ (lane>>3)
    // (inverse swizzle so LDS-linear holds swizzled data; read applies the
    //  same XOR). row&7 == lane>>3 since bases are multiples of 8.
    const int lr = lane >> 3;
    const int lsl = (lane & 7) ^ lr;
    const u16* gA = A  + (m0 + w * 16 + lr) * (long)lda  + lsl * 8;
    const u16* gB = BT + (n0 + w * 16 + lr) * (long)ldbt + lsl * 8;

    f32x4 acc[8][4];
#pragma unroll
    for (int i = 0; i < 8; ++i)
#pragma unroll
        for (int j = 0; j < 4; ++j)
#pragma unroll
            for (int r = 0; r < 4; ++r) acc[i][j][r] = 0.0f;

    // unit g: tile=g>>2, u=g&3 (u0:A-h0, u1:A-h1, u2:B-h0, u3:B-h1). 2 gloads.
    auto STAGE = [&](int g) {
        const int tau = g >> 2, u = g & 3;
        const int b = tau & 1, hf = u & 1;
        const long kt = (long)tau << 6;
        if (u < 2) {
            const u16* s = gA + (long)hf * 128 * lda + kt;
            u16* d = &bufA[b][(hf * 128 + w * 16) * 64];
            gload_lds16(s, d);
            gload_lds16(s + 8 * (long)lda, d + 512);
        } else {
            const u16* s = gB + (long)hf * 128 * ldbt + kt;
            u16* d = &bufB[b][(hf * 128 + w * 16) * 64];
            gload_lds16(s, d);
            gload_lds16(s + 8 * (long)ldbt, d + 512);
        }
    };
    // fragment reads: row*64 + ((quad + kk*4) ^ (row&7))*8, row&7 == fr&7
    auto RD_A = [&](int b, int mi, int kk) -> f16x8 {
        return *(const f16x8*)&bufA[b][(wm * 128 + mi * 16 + fr) * 64
                                       + (((quad + kk * 4) ^ f7) << 3)];
    };
    auto RD_B = [&](int b, int nj, int kk) -> f16x8 {
        return *(const f16x8*)&bufB[b][(wn * 64 + nj * 16 + fr) * 64
                                       + (((quad + kk * 4) ^ f7) << 3)];
    };

    const int NT = K >> 6;                 // 16 for K=1024
    const int GMAX = 4 * NT;

    // prologue: tile0 (u0-3) + tile1.u0; gate tile0 landed (vmcnt(2) leaves
    // tile1.u0's 2 loads in flight)
    for (int g = 0; g < 5; ++g) STAGE(g);
    asm volatile("s_waitcnt vmcnt(2)" ::: "memory");
    __builtin_amdgcn_s_barrier();
    __builtin_amdgcn_sched_barrier(0);

    f16x8 af[4][2], bf[4][2];
    for (int t = 0; t < NT; ++t) {
        const int b = t & 1;
        const int gb = 5 + 4 * t;

        // ---- P0: read af0-3 + bf0-1 (12), stage tile(t+1).u1 ----
#pragma unroll
        for (int mi = 0; mi < 4; ++mi) {
            af[mi][0] = RD_A(b, mi, 0); af[mi][1] = RD_A(b, mi, 1);
        }
#pragma unroll
        for (int nj = 0; nj < 2; ++nj) {
            bf[nj][0] = RD_B(b, nj, 0); bf[nj][1] = RD_B(b, nj, 1);
        }
        if (gb < GMAX) STAGE(gb);
        SYNC_IN();
        __builtin_amdgcn_s_setprio(1);
#pragma unroll
        for (int mi = 0; mi < 4; ++mi)
#pragma unroll
            for (int nj = 0; nj < 2; ++nj) {
                acc[mi][nj] = __builtin_amdgcn_mfma_f32_16x16x32_f16(
                    af[mi][0], bf[nj][0], acc[mi][nj], 0, 0, 0);
                acc[mi][nj] = __builtin_amdgcn_mfma_f32_16x16x32_f16(
                    af[mi][1], bf[nj][1], acc[mi][nj], 0, 0, 0);
            }
        __builtin_amdgcn_s_setprio(0);
        BAR2();

        // ---- P1: read bf2-3 (4), stage tile(t+1).u2 ----
#pragma unroll
        for (int nj = 2; nj < 4; ++nj) {
            bf[nj][0] = RD_B(b, nj, 0); bf[nj][1] = RD_B(b, nj, 1);
        }
        if (gb + 1 < GMAX) STAGE(gb + 1);
        SYNC_IN();
        __builtin_amdgcn_s_setprio(1);
#pragma unroll
        for (int mi = 0; mi < 4; ++mi)
#pragma unroll
            for (int nj = 2; nj < 4; ++nj) {
                acc[mi][nj] = __builtin_amdgcn_mfma_f32_16x16x32_f16(
                    af[mi][0], bf[nj][0], acc[mi][nj], 0, 0, 0);
                acc[mi][nj] = __builtin_amdgcn_mfma_f32_16x16x32_f16(
                    af[mi][1], bf[nj][1], acc[mi][nj], 0, 0, 0);
            }
        __builtin_amdgcn_s_setprio(0);
        BAR2();

        // ---- P2: read af4-7 (8), stage tile(t+1).u3 ----
#pragma unroll
        for (int mi = 0; mi < 4; ++mi) {
            af[mi][0] = RD_A(b, mi + 4, 0); af[mi][1] = RD_A(b, mi + 4, 1);
        }
        if (gb + 2 < GMAX) STAGE(gb + 2);
        SYNC_IN();
        __builtin_amdgcn_s_setprio(1);
#pragma unroll
        for (int mi = 0; mi < 4; ++mi)
#pragma unroll
            for (int nj = 2; nj < 4; ++nj) {
                acc[mi + 4][nj] = __builtin_amdgcn_mfma_f32_16x16x32_f16(
                    af[mi][0], bf[nj][0], acc[mi + 4][nj], 0, 0, 0);
                acc[mi + 4][nj] = __builtin_amdgcn_mfma_f32_16x16x32_f16(
                    af[mi][1], bf[nj][1], acc[mi + 4][nj], 0, 0, 0);
            }
        __builtin_amdgcn_s_setprio(0);
        BAR2();

        // ---- P3: no reads, stage tile(t+2).u0 (buf b: last reads drained
        //      by P2's lgkmcnt+barrier), gate next tile with vmcnt(2) ----
        if (gb + 3 < GMAX) STAGE(gb + 3);
        __builtin_amdgcn_s_barrier();
        __builtin_amdgcn_sched_barrier(0);
        __builtin_amdgcn_s_setprio(1);
#pragma unroll
        for (int mi = 0; mi < 4; ++mi)
#pragma unroll
            for (int nj = 0; nj < 2; ++nj) {
                acc[mi + 4][nj] = __builtin_amdgcn_mfma_f32_16x16x32_f16(
                    af[mi][0], bf[nj][0], acc[mi + 4][nj], 0, 0, 0);
                acc[mi + 4][nj] = __builtin_amdgcn_mfma_f32_16x16x32_f16(
                    af[mi][1], bf[nj][1], acc[mi + 4][nj], 0, 0, 0);
            }
        __builtin_amdgcn_s_setprio(0);
        if (t < NT - 2) {
            asm volatile("s_waitcnt vmcnt(2)" ::: "memory");
        } else if (t == NT - 2) {
            asm volatile("s_waitcnt vmcnt(0)" ::: "memory");
        }
        BAR2();
    }

    // C/D: col = lane&15 (+16*nj), row = quad*4 + r (+16*mi)
    const long cm = m0 + wm * 128 + quad * 4;
    const long cn = n0 + wn * 64 + fr;

    if (ROPE && cn < 2048) {
        const float invf0 = exp2f(-(float)fr * ROPE_K);
        const float invf1 = exp2f(-(float)(fr + 16) * ROPE_K);
#pragma unroll
        for (int mi = 0; mi < 8; ++mi)
#pragma unroll
            for (int r = 0; r < 4; ++r) {
                long row = cm + mi * 16 + r;
                float n = (float)(int)(row & (SEQ - 1));
                float s0, c0, s1, c1;
                __sincosf(n * invf0, &s0, &c0);
                __sincosf(n * invf1, &s1, &c1);
                float x1 = acc[mi][0][r], x2 = acc[mi][2][r];
                float x3 = acc[mi][1][r], x4 = acc[mi][3][r];
                float u1 = (x1 * c0 - x2 * s0) * SCALE_F;
                float u2 = (x1 * s0 + x2 * c0) * SCALE_F;
                float u3 = (x3 * c1 - x4 * s1) * SCALE_F;
                float u4 = (x3 * s1 + x4 * c1) * SCALE_F;
                u1 = (u1 > 0.0f) ? (u1 + 1.0f) : __expf(u1);
                u2 = (u2 > 0.0f) ? (u2 + 1.0f) : __expf(u2);
                u3 = (u3 > 0.0f) ? (u3 + 1.0f) : __expf(u3);
                u4 = (u4 > 0.0f) ? (u4 + 1.0f) : __expf(u4);
                CT* pr = C + row * ldc + cn;
                storeC(pr, u1); storeC(pr + 16, u3);
                storeC(pr + 32, u2); storeC(pr + 48, u4);
            }
    } else {
#pragma unroll
        for (int mi = 0; mi < 8; ++mi)
#pragma unroll
            for (int nj = 0; nj < 4; ++nj)
#pragma unroll
                for (int r = 0; r < 4; ++r)
                    storeC(&C[(cm + mi * 16 + r) * ldc + cn + nj * 16], acc[mi][nj][r]);
    }
}

// ---------------------------------------------------------------------------
// Per-(b,h,chunk): S[m][d] = sum_t V[t][m] K[t][d]  (= (K^T V)^T, fp16),
// ksum[d] = sum_t K[t][d] (fp32). MFMA 16x16x32.
// ---------------------------------------------------------------------------
__global__ __launch_bounds__(256)
void chunk_sums_mfma(const u16* __restrict__ qkv,
                     u16* __restrict__ S, float* __restrict__ ksum)
{
    __shared__ u16 Kt[64][72];   // [d][t]
    __shared__ u16 Vt[64][72];   // [m][t]

    const int blk = blockIdx.x;
    const int c = blk & 63, bh = blk >> 6;
    const int b = bh >> 4, h = bh & 15;
    const int tid = threadIdx.x;
    const long base = (long)(b * SEQ + c * CHUNK) * QKVC + h * HDIM;

#pragma unroll
    for (int j = 0; j < 4; ++j) {
        int i4 = (j * 256 + tid) * 4;
        int t = i4 >> 6, d = i4 & 63;
        const u16* src = qkv + base + (long)t * QKVC + d;
        ushort4 kk = *(const ushort4*)(src + DMODEL);
        ushort4 vv = *(const ushort4*)(src + 2 * DMODEL);
        Kt[d + 0][t] = kk.x; Kt[d + 1][t] = kk.y;
        Kt[d + 2][t] = kk.z; Kt[d + 3][t] = kk.w;
        Vt[d + 0][t] = vv.x; Vt[d + 1][t] = vv.y;
        Vt[d + 2][t] = vv.z; Vt[d + 3][t] = vv.w;
    }
    __syncthreads();

    const int w = tid >> 6, lane = tid & 63;
    const int fr = lane & 15, quad = lane >> 4;

    // D[m][d] = sum_t Vt[m][t] * K[t][d];  A = Vt, B-op layout [d][t] = Kt
    f16x8 af0 = *(const f16x8*)&Vt[w * 16 + fr][quad * 8];
    f16x8 af1 = *(const f16x8*)&Vt[w * 16 + fr][32 + quad * 8];
    f32x4 acc[4];
#pragma unroll
    for (int j = 0; j < 4; ++j)
#pragma unroll
        for (int r = 0; r < 4; ++r) acc[j][r] = 0.0f;
#pragma unroll
    for (int j = 0; j < 4; ++j) {
        f16x8 b0 = *(const f16x8*)&Kt[j * 16 + fr][quad * 8];
        f16x8 b1 = *(const f16x8*)&Kt[j * 16 + fr][32 + quad * 8];
        acc[j] = __builtin_amdgcn_mfma_f32_16x16x32_f16(af0, b0, acc[j], 0, 0, 0);
        acc[j] = __builtin_amdgcn_mfma_f32_16x16x32_f16(af1, b1, acc[j], 0, 0, 0);
    }
    const long sb = (long)blk * 4096;
    const int mrow = w * 16 + quad * 4;
#pragma unroll
    for (int j = 0; j < 4; ++j)
#pragma unroll
        for (int r = 0; r < 4; ++r)
            S[sb + (mrow + r) * 64 + j * 16 + fr] = f2h(acc[j][r]);

    if (tid < 64) {
        float s = 0.0f;
        for (int t = 0; t < 64; ++t) s += h2f(Kt[tid][t]);
        ksum[(long)blk * 64 + tid] = s;
    }
}

// ---------------------------------------------------------------------------
// Exclusive prefix scan over chunks (per bh): S (fp16) and ksum (fp32).
// ---------------------------------------------------------------------------
__global__ __launch_bounds__(256)
void scan_kernel(u16* __restrict__ S, float* __restrict__ ksum)
{
    const int blk = blockIdx.x;
    const int slice = blk & 15, bh = blk >> 4;
    const int p = slice * 256 + threadIdx.x;
    const long base = (long)bh * NCHUNK * 4096 + p;
    float acc = 0.0f;
    for (int c = 0; c < NCHUNK; ++c) {
        long idx = base + (long)c * 4096;
        float tmp = h2f(S[idx]);
        S[idx] = f2h(acc);
        acc += tmp;
    }
    if (slice == 0 && threadIdx.x < 64) {
        const long kb = (long)bh * NCHUNK * 64 + threadIdx.x;
        float ka = 0.0f;
        for (int c = 0; c < NCHUNK; ++c) {
            float t = ksum[kb + (long)c * 64];
            ksum[kb + (long)c * 64] = ka;
            ka += t;
        }
    }
}

// ---------------------------------------------------------------------------
// Per-(b,h,chunk) output via MFMA:
//   Sc = causal(Q K^T); out = Sc @ V + Q @ KV_prefix; out /= denom.
// In place over the q slice. S holds KV^T prefix ([m][d]).
// ---------------------------------------------------------------------------
__global__ __launch_bounds__(256)
void chunk_out_mfma(u16* __restrict__ qkv,
                    const u16* __restrict__ S, const float* __restrict__ ksum)
{
    __shared__ u16 Qs[64][72];    // [t][d]
    __shared__ u16 Ks[64][72];    // [s][d]  (B-op for QK^T)
    __shared__ u16 Vt[64][72];    // [m][s]  (B-op for Sc@V)
    __shared__ u16 KVt[64][72];   // [m][d]  (B-op for Q@KV)
    __shared__ u16 Sch[64][72];   // [t][s]  masked scores (A-op for Sc@V)
    __shared__ float kss[64];
    __shared__ float den[64];

    const int blk = blockIdx.x;
    const int c = blk & 63, bh = blk >> 6;
    const int b = bh >> 4, h = bh & 15;
    const int tid = threadIdx.x;
    const long base = (long)(b * SEQ + c * CHUNK) * QKVC + h * HDIM;

#pragma unroll
    for (int j = 0; j < 4; ++j) {
        int i4 = (j * 256 + tid) * 4;
        int t = i4 >> 6, d = i4 & 63;
        const u16* src = qkv + base + (long)t * QKVC + d;
        *(ushort4*)&Qs[t][d] = *(const ushort4*)(src);
        *(ushort4*)&Ks[t][d] = *(const ushort4*)(src + DMODEL);
        ushort4 vv = *(const ushort4*)(src + 2 * DMODEL);
        Vt[d + 0][t] = vv.x; Vt[d + 1][t] = vv.y;
        Vt[d + 2][t] = vv.z; Vt[d + 3][t] = vv.w;
        *(ushort4*)&KVt[t][d] = *(const ushort4*)(S + (long)blk * 4096 + i4);
    }
    if (tid < 64) kss[tid] = ksum[(long)blk * 64 + tid];
    __syncthreads();

    const int w = tid >> 6, lane = tid & 63;
    const int fr = lane & 15, quad = lane >> 4;
    const int trow = w * 16 + quad * 4;   // C-layout row base

    // --- Sc = Q K^T (wave w: rows w*16..+16) ---
    f16x8 aq0 = *(const f16x8*)&Qs[w * 16 + fr][quad * 8];
    f16x8 aq1 = *(const f16x8*)&Qs[w * 16 + fr][32 + quad * 8];
    f32x4 sc[4];
#pragma unroll
    for (int j = 0; j < 4; ++j)
#pragma unroll
        for (int r = 0; r < 4; ++r) sc[j][r] = 0.0f;
#pragma unroll
    for (int j = 0; j < 4; ++j) {
        f16x8 b0 = *(const f16x8*)&Ks[j * 16 + fr][quad * 8];
        f16x8 b1 = *(const f16x8*)&Ks[j * 16 + fr][32 + quad * 8];
        sc[j] = __builtin_amdgcn_mfma_f32_16x16x32_f16(aq0, b0, sc[j], 0, 0, 0);
        sc[j] = __builtin_amdgcn_mfma_f32_16x16x32_f16(aq1, b1, sc[j], 0, 0, 0);
    }
    // causal mask + store fp16
#pragma unroll
    for (int j = 0; j < 4; ++j)
#pragma unroll
        for (int r = 0; r < 4; ++r) {
            int t = trow + r, s = j * 16 + fr;
            Sch[t][s] = f2h(s <= t ? sc[j][r] : 0.0f);
        }
    __syncthreads();

    // --- denominators ---
    if (tid < 64) {
        float dn = 0.0f;
        for (int d = 0; d < 64; ++d) dn += h2f(Qs[tid][d]) * kss[d];
        for (int s = 0; s <= tid; ++s) dn += h2f(Sch[tid][s]);
        den[tid] = 1.0f / fmaxf(dn, 1e-6f);
    }
    __syncthreads();

    // --- out = Sch @ V + Q @ KV ---
    f16x8 as0 = *(const f16x8*)&Sch[w * 16 + fr][quad * 8];
    f16x8 as1 = *(const f16x8*)&Sch[w * 16 + fr][32 + quad * 8];
    f32x4 oc[4];
#pragma unroll
    for (int j = 0; j < 4; ++j)
#pragma unroll
        for (int r = 0; r < 4; ++r) oc[j][r] = 0.0f;
#pragma unroll
    for (int j = 0; j < 4; ++j) {
        f16x8 b0 = *(const f16x8*)&Vt[j * 16 + fr][quad * 8];
        f16x8 b1 = *(const f16x8*)&Vt[j * 16 + fr][32 + quad * 8];
        oc[j] = __builtin_amdgcn_mfma_f32_16x16x32_f16(as0, b0, oc[j], 0, 0, 0);
        oc[j] = __builtin_amdgcn_mfma_f32_16x16x32_f16(as1, b1, oc[j], 0, 0, 0);
        f16x8 k0 = *(const f16x8*)&KVt[j * 16 + fr][quad * 8];
        f16x8 k1 = *(const f16x8*)&KVt[j * 16 + fr][32 + quad * 8];
        oc[j] = __builtin_amdgcn_mfma_f32_16x16x32_f16(aq0, k0, oc[j], 0, 0, 0);
        oc[j] = __builtin_amdgcn_mfma_f32_16x16x32_f16(aq1, k1, oc[j], 0, 0, 0);
    }
    // scale by 1/denom, store in place over q slice
#pragma unroll
    for (int j = 0; j < 4; ++j)
#pragma unroll
        for (int r = 0; r < 4; ++r) {
            int t = trow + r;
            qkv[base + (long)t * QKVC + j * 16 + fr] = f2h(oc[j][r] * den[t]);
        }
}

// ---------------------------------------------------------------------------
extern "C" void kernel_launch(void* const* d_in, const int* in_sizes, int n_in,
                              void* d_out, int out_size, void* d_ws, size_t ws_size,
                              hipStream_t stream)
{
    const float* x     = (const float*)d_in[0];
    const float* w_qkv = (const float*)d_in[1];
    const float* w_out = (const float*)d_in[2];
    float* out = (float*)d_out;

    // Workspace: qkv fp16 only (100.7 MB — proven-safe footprint).
    u16* qkv = (u16*)d_ws;
    // d_out doubles as scratch before the final GEMM writes it:
    u16* xf16  = (u16*)d_out;                         // 16384*1024 fp16
    u16* wqkvT = xf16 + (size_t)NTOK * DMODEL;        // 3072*1024 fp16
    u16* S     = (u16*)d_out;                         // 64*64*4096 fp16 (alias xf16)
    float* ksum = (float*)((char*)d_out + 33554432);  // 64*64*64 fp32 (alias wqkvT)
    // w_outT lives in the dead k-slice of qkv (rows 0..1023, cols 1024..2047)
    u16* woutT = qkv + 1024;                          // [n][k], row stride 3072

    dim3 blk(256);
    dim3 gblk(512);

    // 0) conversions for GEMM1
    convert_f32_f16<<<NTOK * DMODEL / 1024, blk, 0, stream>>>(x, xf16);
    transpose_convert<<<dim3(QKVC / 64, DMODEL / 64), blk, 0, stream>>>(
        w_qkv, QKVC, wqkvT, DMODEL);

    // 1) qkv = x @ w_qkv with fused RoPE+elu on q,k cols (identity swizzle)
    gemm_mfma<u16, true, false><<<dim3(QKVC / 256, NTOK / 256), gblk, 0, stream>>>(
        xf16, DMODEL, wqkvT, DMODEL, qkv, QKVC, DMODEL);

    // 2) chunk-parallel linear attention (all MFMA)
    chunk_sums_mfma<<<64 * NCHUNK, blk, 0, stream>>>(qkv, S, ksum);
    scan_kernel<<<64 * 16, blk, 0, stream>>>(S, ksum);
    chunk_out_mfma<<<64 * NCHUNK, blk, 0, stream>>>(qkv, S, ksum);

    // 3) w_out transpose into dead k-slice, then out = attn @ w_out (T1 swizzle)
    transpose_convert<<<dim3(DMODEL / 64, DMODEL / 64), blk, 0, stream>>>(
        w_out, DMODEL, woutT, QKVC);
    gemm_mfma<float, false, true><<<dim3(DMODEL / 256, NTOK / 256), gblk, 0, stream>>>(
        qkv, QKVC, woutT, QKVC, out, DMODEL, DMODEL);
}